// Round 9
// baseline (167.766 us; speedup 1.0000x reference)
//
#include <hip/hip_runtime.h>
#include <hip/hip_bf16.h>
#include <math.h>

#define D 128
#define NT 3
#define KTOT (D * (NT + 1))   // 512
#define TM 32                 // nodes per fused block / bucket
#define BCAP 320              // bucket capacity (mean 192, +9 sigma)
#define NCAP 32               // per-node LDS csr capacity

typedef __attribute__((ext_vector_type(8))) __bf16 bf16x8;
typedef __attribute__((ext_vector_type(4))) float f32x4;

__device__ inline unsigned short f2bf(float f) {
    unsigned int u = __float_as_uint(f);
    unsigned int r = (u + 0x7FFFu + ((u >> 16) & 1u)) >> 16;
    return (unsigned short)r;
}
__device__ inline float bf2f(unsigned int low16) {
    return __uint_as_float(low16 << 16);
}

// ---------------- zero helper (fallback path) ----------------
__global__ void zero_kernel(float* __restrict__ p, long long n4) {
    long long i = (long long)blockIdx.x * blockDim.x + threadIdx.x;
    long long stride = (long long)gridDim.x * blockDim.x;
    float4 z = make_float4(0.f, 0.f, 0.f, 0.f);
    for (; i < n4; i += stride) ((float4*)p)[i] = z;
}

// ---------------- prep: softmax(attention) -> wcat, biasb, bfrag; zero counters ----------------
__global__ void prep_kernel(const float* __restrict__ W_edge, const float* __restrict__ b_edge,
                            const float* __restrict__ W_self, const float* __restrict__ b_self,
                            const float* __restrict__ attention,
                            float* __restrict__ wcat, float* __restrict__ biasb,
                            unsigned short* __restrict__ bfrag,
                            int* __restrict__ zeroMe, int zeroN) {
    float a0 = attention[0], a1 = attention[1], a2 = attention[2], a3 = attention[3];
    float m = fmaxf(fmaxf(a0, a1), fmaxf(a2, a3));
    float e0 = expf(a0 - m), e1 = expf(a1 - m), e2 = expf(a2 - m), e3 = expf(a3 - m);
    float inv = 1.f / (e0 + e1 + e2 + e3);
    float at[4] = {e0 * inv, e1 * inv, e2 * inv, e3 * inv};

    int idx0 = blockIdx.x * blockDim.x + threadIdx.x;
    int stride = gridDim.x * blockDim.x;
    if (zeroMe) {
        for (int i = idx0; i < zeroN; i += stride) zeroMe[i] = 0;
    }
    for (int i = idx0; i < KTOT * D; i += stride) {
        int k = i >> 7, j = i & (D - 1);
        float v;
        if (k < D) {
            v = at[NT] * W_self[k * D + j];
        } else {
            int t = (k - D) >> 7;
            int kk = (k - D) & (D - 1);
            v = at[t] * W_edge[(t * D + kk) * D + j];
        }
        wcat[i] = v;
    }
    for (int i = idx0; i < KTOT; i += stride) {
        if (i < NT * D) {
            int t = i >> 7, j = i & (D - 1);
            biasb[i] = at[t] * b_edge[t * D + j];
        } else {
            biasb[i] = at[NT] * b_self[i - NT * D];
        }
    }
    if (bfrag) {
        // bfrag: [(step*8+cf)*64+lane]*8 ; B[k][col], col=cf*16+(l&15), k=step*32+(l>>4)*8+j
        for (int i = idx0; i < 16 * 8 * 64; i += stride) {
            int l = i & 63;
            int cf = (i >> 6) & 7;
            int step = i >> 9;
            int col = cf * 16 + (l & 15);
            int kb = step * 32 + ((l >> 4) * 8);
#pragma unroll
            for (int j = 0; j < 8; ++j) {
                int k = kb + j;
                float v;
                if (k < D) {
                    v = at[NT] * W_self[k * D + col];
                } else {
                    int t = (k - D) >> 7;
                    int kk = (k - D) & (D - 1);
                    v = at[t] * W_edge[(t * D + kk) * D + col];
                }
                bfrag[(size_t)i * 8 + j] = f2bf(v);
            }
        }
    }
}

// ---------------- pass A: x->bf16 xb (blocks < XB) + edge binning into 32-node buckets ----------------
__global__ __launch_bounds__(256) void xcvt_bin_kernel(
    const float* __restrict__ x, unsigned short* __restrict__ xb, int nN,
    const int* __restrict__ ei, const int* __restrict__ et, const float* __restrict__ ew,
    int* __restrict__ bcnt, int2* __restrict__ bucket,
    int* __restrict__ ovfc, int* __restrict__ ovflist, int nE, int XB) {
    int b = blockIdx.x;
    if (b < XB) {
        int i = b * 256 + threadIdx.x;
        int total = nN * (D / 4);
        int stride = XB * 256;
        for (; i < total; i += stride) {
            int n = i >> 5;
            int c4 = (i & 31) * 4;
            float4 v = *(const float4*)(x + (size_t)n * D + c4);
            ushort4 o;
            o.x = f2bf(v.x); o.y = f2bf(v.y); o.z = f2bf(v.z); o.w = f2bf(v.w);
            *(ushort4*)(xb + (size_t)n * D + c4) = o;
        }
    } else {
        int e = (b - XB) * 256 + threadIdx.x;
        if (e >= nE) return;
        int dst = ei[nE + e];
        int bu = dst >> 5;
        int pos = atomicAdd(bcnt + bu, 1);
        if (pos < BCAP) {
            int src = ei[e];
            int t = et[e];
            bucket[(size_t)bu * BCAP + pos] =
                make_int2(src | (t << 20) | ((dst & 31) << 22), __float_as_int(ew[e]));
        } else {
            int o = atomicAdd(ovfc, 1);
            ovflist[o] = e;
        }
    }
}

// ---------------- pass B: fused LDS-csr build + gather + MFMA GEMM + epilogue ----------------
// One block per 32-node bucket, 512 threads (8 waves).
// LDS: A-tile 32x1024B @0 | B dbuf 2x8192 @32768 | s[96]f32 @49152 | lcsr 32x32 int2 @49536
//      | ldeg[32] @57728 | lovf[320] int2 @57856 | lovfc @60416  => 60420 B, 2 blocks/CU.
__global__ __launch_bounds__(512, 4) void fusedB_kernel(
    const unsigned short* __restrict__ xb, const int2* __restrict__ bucket,
    const int* __restrict__ bcnt, const unsigned short* __restrict__ bfrag,
    const float* __restrict__ biasb,
    const int* __restrict__ ei, const int* __restrict__ et, const float* __restrict__ ew,
    const int* __restrict__ ovfc, const int* __restrict__ ovflist,
    float* __restrict__ out, int nN, int nE) {
    __shared__ unsigned char lds[60424];
    float* sL = (float*)(lds + 49152);
    int2* lcsr = (int2*)(lds + 49536);
    int* ldeg = (int*)(lds + 57728);
    int2* lovf = (int2*)(lds + 57856);
    int* lovfc = (int*)(lds + 60416);

    int t = threadIdx.x;
    int w = t >> 6;
    int lane = t & 63;
    int row0 = blockIdx.x * TM;

#define BSTAGE(buf, st_) do {                                                                     \
        const unsigned short* gsrc = bfrag + (size_t)(st_) * 4096 + w * 512 + lane * 8;           \
        unsigned char* ldst = lds + 32768 + (buf) * 8192 + w * 1024;                              \
        __builtin_amdgcn_global_load_lds((const __attribute__((address_space(1))) void*)gsrc,     \
                                         (__attribute__((address_space(3))) void*)ldst, 16, 0, 0);\
    } while (0)

    BSTAGE(0, 0);   // in flight across the whole gather phase

    if (t < 32) ldeg[t] = 0;
    if (t == 32) *lovfc = 0;
    __syncthreads();

    // ---- build per-node lists in LDS from this block's bucket ----
    int cnt = bcnt[blockIdx.x];
    if (cnt > BCAP) cnt = BCAP;
    for (int i = t; i < cnt; i += 512) {
        int2 eo = bucket[(size_t)blockIdx.x * BCAP + i];
        int lr = (eo.x >> 22) & 31;
        int pos = atomicAdd(&ldeg[lr], 1);
        if (pos < NCAP) lcsr[lr * NCAP + pos] = eo;
        else { int lp = atomicAdd(lovfc, 1); lovf[lp] = eo; }   // lp < cnt <= 320, always in bounds
    }
    __syncthreads();

    // ---- gather: wave w owns nodes row0 + w*4 .. +3 (16 lanes per node) ----
    int gl = lane & 15;
    int gbase = lane & 48;
    int lrow = w * 4 + (lane >> 4);
    int node = row0 + lrow;
    int nclamp = (node < nN) ? node : (nN - 1);
    int dg = ldeg[lrow];
    if (dg > NCAP) dg = NCAP;
    int2 mA = (gl < dg) ? lcsr[lrow * NCAP + gl] : make_int2(0, 0);
    int2 mB = (gl + 16 < dg) ? lcsr[lrow * NCAP + gl + 16] : make_int2(0, 0);

    float ac0[8], ac1[8], ac2[8];
#pragma unroll
    for (int j = 0; j < 8; ++j) { ac0[j] = 0.f; ac1[j] = 0.f; ac2[j] = 0.f; }
    float sw0 = 0.f, sw1 = 0.f, sw2 = 0.f;

    for (int i = 0; i < dg; i += 2) {
        int slA = gbase + (i & 15);
        int exA = __shfl((i < 16) ? mA.x : mB.x, slA);
        int ewA = __shfl((i < 16) ? mA.y : mB.y, slA);
        int srcA = exA & 0xFFFFF;
        if (srcA >= nN) srcA = 0;
        float wA = __int_as_float(ewA);
        int tA = (exA >> 20) & 3;
        bool actB = (i + 1 < dg);
        int slB = gbase + ((i + 1) & 15);
        int exB = __shfl((i + 1 < 16) ? mA.x : mB.x, slB);
        int ewB = __shfl((i + 1 < 16) ? mA.y : mB.y, slB);
        int srcB = exB & 0xFFFFF;
        if (!actB || srcB >= nN) srcB = 0;
        float wB = actB ? __int_as_float(ewB) : 0.f;
        int tB = (exB >> 20) & 3;

        uint4 xa = *(const uint4*)(xb + (size_t)srcA * D + gl * 8);
        uint4 xbv = *(const uint4*)(xb + (size_t)srcB * D + gl * 8);

        float wA0 = (tA == 0) ? wA : 0.f;
        float wA1 = (tA == 1) ? wA : 0.f;
        float wA2 = (tA == 2) ? wA : 0.f;
        float wB0 = (tB == 0) ? wB : 0.f;
        float wB1 = (tB == 1) ? wB : 0.f;
        float wB2 = (tB == 2) ? wB : 0.f;
        sw0 += wA0 + wB0; sw1 += wA1 + wB1; sw2 += wA2 + wB2;

        float f0, f1;
#define ACCUM(u, j0, j1, w0_, w1_, w2_)                                   \
        f0 = __uint_as_float((u) << 16);                                  \
        f1 = __uint_as_float((u) & 0xFFFF0000u);                          \
        ac0[j0] = fmaf(w0_, f0, ac0[j0]); ac0[j1] = fmaf(w0_, f1, ac0[j1]); \
        ac1[j0] = fmaf(w1_, f0, ac1[j0]); ac1[j1] = fmaf(w1_, f1, ac1[j1]); \
        ac2[j0] = fmaf(w2_, f0, ac2[j0]); ac2[j1] = fmaf(w2_, f1, ac2[j1]);
        ACCUM(xa.x, 0, 1, wA0, wA1, wA2)
        ACCUM(xa.y, 2, 3, wA0, wA1, wA2)
        ACCUM(xa.z, 4, 5, wA0, wA1, wA2)
        ACCUM(xa.w, 6, 7, wA0, wA1, wA2)
        ACCUM(xbv.x, 0, 1, wB0, wB1, wB2)
        ACCUM(xbv.y, 2, 3, wB0, wB1, wB2)
        ACCUM(xbv.z, 4, 5, wB0, wB1, wB2)
        ACCUM(xbv.w, 6, 7, wB0, wB1, wB2)
#undef ACCUM
    }

    // ---- write A tile (chunk-XOR swizzled, both sides — rule #21) ----
    {
        int swz = lrow & 15;
        uint4 xo = *(const uint4*)(xb + (size_t)nclamp * D + gl * 8);   // own x row, already bf16
        *(uint4*)(lds + lrow * 1024 + ((gl ^ swz) << 4)) = xo;
        uint4 o;
#define PACKST(arr, tt)                                                                \
        o.x = (unsigned int)f2bf(arr[0]) | ((unsigned int)f2bf(arr[1]) << 16);         \
        o.y = (unsigned int)f2bf(arr[2]) | ((unsigned int)f2bf(arr[3]) << 16);         \
        o.z = (unsigned int)f2bf(arr[4]) | ((unsigned int)f2bf(arr[5]) << 16);         \
        o.w = (unsigned int)f2bf(arr[6]) | ((unsigned int)f2bf(arr[7]) << 16);         \
        *(uint4*)(lds + lrow * 1024 + 256 + (tt) * 256 + ((gl ^ swz) << 4)) = o;
        PACKST(ac0, 0)
        PACKST(ac1, 1)
        PACKST(ac2, 2)
#undef PACKST
        if (gl < 3) {
            float sv = (gl == 0) ? sw0 : ((gl == 1) ? sw1 : sw2);
            sL[lrow * NT + gl] = sv;
        }
    }
    __syncthreads();

    // ---- overflow patches (both empty in practice; fully correct for any data) ----
    int lcnt = *lovfc;
    int gcnt = *ovfc;
    if (lcnt > 0 || gcnt > 0) {
        if (w == 0 && lane < 16) {
            for (int i = 0; i < lcnt; ++i) {
                int2 eo = lovf[i];
                int lr = (eo.x >> 22) & 31;
                int tt = (eo.x >> 20) & 3;
                int src = eo.x & 0xFFFFF;
                float wt = __int_as_float(eo.y);
                uint4* p = (uint4*)(lds + lr * 1024 + 256 + tt * 256 + ((lane ^ (lr & 15)) << 4));
                uint4 cu = *p;
                uint4 xr = *(const uint4*)(xb + (size_t)src * D + lane * 8);
                float f0 = bf2f(cu.x & 0xFFFF) + wt * bf2f(xr.x & 0xFFFF);
                float f1 = bf2f(cu.x >> 16)    + wt * bf2f(xr.x >> 16);
                float f2 = bf2f(cu.y & 0xFFFF) + wt * bf2f(xr.y & 0xFFFF);
                float f3 = bf2f(cu.y >> 16)    + wt * bf2f(xr.y >> 16);
                float f4 = bf2f(cu.z & 0xFFFF) + wt * bf2f(xr.z & 0xFFFF);
                float f5 = bf2f(cu.z >> 16)    + wt * bf2f(xr.z >> 16);
                float f6 = bf2f(cu.w & 0xFFFF) + wt * bf2f(xr.w & 0xFFFF);
                float f7 = bf2f(cu.w >> 16)    + wt * bf2f(xr.w >> 16);
                cu.x = (unsigned int)f2bf(f0) | ((unsigned int)f2bf(f1) << 16);
                cu.y = (unsigned int)f2bf(f2) | ((unsigned int)f2bf(f3) << 16);
                cu.z = (unsigned int)f2bf(f4) | ((unsigned int)f2bf(f5) << 16);
                cu.w = (unsigned int)f2bf(f6) | ((unsigned int)f2bf(f7) << 16);
                *p = cu;
                if (lane == 0) sL[lr * NT + tt] += wt;
            }
            for (int i = 0; i < gcnt; ++i) {
                int e = ovflist[i];
                int dst = ei[nE + e];
                if (dst >= row0 && dst < row0 + TM && dst < nN) {
                    int tt = et[e];
                    float wt = ew[e];
                    int src = ei[e];
                    int lr = dst - row0;
                    uint4* p = (uint4*)(lds + lr * 1024 + 256 + tt * 256 + ((lane ^ (lr & 15)) << 4));
                    uint4 cu = *p;
                    uint4 xr = *(const uint4*)(xb + (size_t)src * D + lane * 8);
                    float f0 = bf2f(cu.x & 0xFFFF) + wt * bf2f(xr.x & 0xFFFF);
                    float f1 = bf2f(cu.x >> 16)    + wt * bf2f(xr.x >> 16);
                    float f2 = bf2f(cu.y & 0xFFFF) + wt * bf2f(xr.y & 0xFFFF);
                    float f3 = bf2f(cu.y >> 16)    + wt * bf2f(xr.y >> 16);
                    float f4 = bf2f(cu.z & 0xFFFF) + wt * bf2f(xr.z & 0xFFFF);
                    float f5 = bf2f(cu.z >> 16)    + wt * bf2f(xr.z >> 16);
                    float f6 = bf2f(cu.w & 0xFFFF) + wt * bf2f(xr.w & 0xFFFF);
                    float f7 = bf2f(cu.w >> 16)    + wt * bf2f(xr.w >> 16);
                    cu.x = (unsigned int)f2bf(f0) | ((unsigned int)f2bf(f1) << 16);
                    cu.y = (unsigned int)f2bf(f2) | ((unsigned int)f2bf(f3) << 16);
                    cu.z = (unsigned int)f2bf(f4) | ((unsigned int)f2bf(f5) << 16);
                    cu.w = (unsigned int)f2bf(f6) | ((unsigned int)f2bf(f7) << 16);
                    *p = cu;
                    if (lane == 0) sL[lr * NT + tt] += wt;
                }
            }
        }
        __syncthreads();
    }

    // ---- GEMM phase (verified round-8 structure): 16 K-steps, wave w -> cols w*16..+15 ----
    int ll = lane & 15;
    int ck = lane >> 4;
    f32x4 acc0 = (f32x4){0.f, 0.f, 0.f, 0.f};
    f32x4 acc1 = (f32x4){0.f, 0.f, 0.f, 0.f};
#pragma unroll 2
    for (int st = 0; st < 16; ++st) {
        int cur = st & 1;
        if (st < 15) BSTAGE(cur ^ 1, st + 1);
        int cc = st * 4 + ck;
        int phys = (cc & 48) | ((cc & 15) ^ ll);
        bf16x8 a0 = *(const bf16x8*)(lds + ll * 1024 + (phys << 4));
        bf16x8 a1 = *(const bf16x8*)(lds + (16 + ll) * 1024 + (phys << 4));
        bf16x8 b = *(const bf16x8*)(lds + 32768 + cur * 8192 + ((w * 64 + lane) << 4));
        acc0 = __builtin_amdgcn_mfma_f32_16x16x32_bf16(a0, b, acc0, 0, 0, 0);
        acc1 = __builtin_amdgcn_mfma_f32_16x16x32_bf16(a1, b, acc1, 0, 0, 0);
        __syncthreads();
    }
#undef BSTAGE

    // ---- epilogue ----
    int colb = w * 16 + ll;
    float bb0 = biasb[colb], bb1 = biasb[D + colb], bb2 = biasb[2 * D + colb], bs4 = biasb[3 * D + colb];
    const float kInvSqrt2 = 0.70710678118654752440f;
#pragma unroll
    for (int fr = 0; fr < 2; ++fr) {
        f32x4 A = fr ? acc1 : acc0;
#pragma unroll
        for (int reg = 0; reg < 4; ++reg) {
            int lr = fr * 16 + ck * 4 + reg;
            long row = (long)row0 + lr;
            if (row >= nN) continue;
            float s0 = sL[lr * NT + 0];
            float s1 = sL[lr * NT + 1];
            float s2 = sL[lr * NT + 2];
            float v = A[reg] + bs4 + s0 * bb0 + s1 * bb1 + s2 * bb2;
            v = 0.5f * v * (1.f + erff(v * kInvSqrt2));
            out[row * D + colb] = v;
        }
    }
}

// ================= FALLBACK PATH (small ws): f32 atomic scatter + f32 GEMM =================
__global__ __launch_bounds__(256) void scatterA_kernel(
    const float* __restrict__ x, const int* __restrict__ ei,
    const int* __restrict__ et, const float* __restrict__ ew,
    float* __restrict__ agg, float* __restrict__ s, int nE) {
    int gtid = blockIdx.x * blockDim.x + threadIdx.x;
    int wave = gtid >> 6;
    int lane = threadIdx.x & 63;
    int nw = (gridDim.x * blockDim.x) >> 6;
    for (int e = wave; e < nE; e += nw) {
        int src = ei[e];
        int dst = ei[nE + e];
        int t = et[e];
        float w = ew[e];
        float2 xv = *(const float2*)(x + (size_t)src * D + lane * 2);
        float* p = agg + (size_t)dst * (NT * D) + t * D + lane * 2;
        unsafeAtomicAdd(p, w * xv.x);
        unsafeAtomicAdd(p + 1, w * xv.y);
        if (lane == 0) unsafeAtomicAdd(s + (size_t)dst * NT + t, w);
    }
}

#define BM 64
#define BK 32
__global__ __launch_bounds__(256) void gemm_gelu_kernel(
    const float* __restrict__ x, const float* __restrict__ agg,
    const float* __restrict__ s, const float* __restrict__ wcat,
    const float* __restrict__ biasb, float* __restrict__ out, int nNodes) {
    __shared__ float As[BK][BM + 1];
    __shared__ float Bs[BK][D];

    int tx = threadIdx.x;
    int row0 = blockIdx.x * BM;
    int cg = tx & 31;
    int rg = tx >> 5;
    int lr = tx >> 3;
    int lc = (tx & 7) * 4;

    float acc[8][4];
#pragma unroll
    for (int i = 0; i < 8; ++i)
#pragma unroll
        for (int j = 0; j < 4; ++j) acc[i][j] = 0.f;

    for (int k0 = 0; k0 < KTOT; k0 += BK) {
        const float* srcBase;
        int strideA, koff;
        if (k0 < D) { srcBase = x; strideA = D; koff = k0; }
        else        { srcBase = agg; strideA = NT * D; koff = k0 - D; }
#pragma unroll
        for (int h = 0; h < 2; ++h) {
            int r = lr + h * 32;
            int node = row0 + r;
            if (node >= nNodes) node = nNodes - 1;
            float4 v = *(const float4*)(srcBase + (size_t)node * strideA + koff + lc);
            As[lc + 0][r] = v.x; As[lc + 1][r] = v.y;
            As[lc + 2][r] = v.z; As[lc + 3][r] = v.w;
        }
        {
            int br = tx >> 5;
            int bc = (tx & 31) * 4;
#pragma unroll
            for (int h = 0; h < 4; ++h) {
                int r = br + h * 8;
                *(float4*)(&Bs[r][bc]) = *(const float4*)(wcat + (size_t)(k0 + r) * D + bc);
            }
        }
        __syncthreads();
#pragma unroll
        for (int kk = 0; kk < BK; ++kk) {
            float4 b = *(const float4*)(&Bs[kk][cg * 4]);
            float a[8];
            *(float4*)(a)     = *(const float4*)(&As[kk][rg * 8]);
            *(float4*)(a + 4) = *(const float4*)(&As[kk][rg * 8 + 4]);
#pragma unroll
            for (int i = 0; i < 8; ++i) {
                acc[i][0] = fmaf(a[i], b.x, acc[i][0]);
                acc[i][1] = fmaf(a[i], b.y, acc[i][1]);
                acc[i][2] = fmaf(a[i], b.z, acc[i][2]);
                acc[i][3] = fmaf(a[i], b.w, acc[i][3]);
            }
        }
        __syncthreads();
    }

    int jc = cg * 4;
    float4 bb0 = *(const float4*)(biasb + 0 * D + jc);
    float4 bb1 = *(const float4*)(biasb + 1 * D + jc);
    float4 bb2 = *(const float4*)(biasb + 2 * D + jc);
    float4 bsv = *(const float4*)(biasb + NT * D + jc);
#pragma unroll
    for (int i = 0; i < 8; ++i) {
        int node = row0 + rg * 8 + i;
        if (node >= nNodes) break;
        float s0 = s[(size_t)node * NT + 0];
        float s1 = s[(size_t)node * NT + 1];
        float s2 = s[(size_t)node * NT + 2];
        float4 r;
        r.x = acc[i][0] + bsv.x + s0 * bb0.x + s1 * bb1.x + s2 * bb2.x;
        r.y = acc[i][1] + bsv.y + s0 * bb0.y + s1 * bb1.y + s2 * bb2.y;
        r.z = acc[i][2] + bsv.z + s0 * bb0.z + s1 * bb1.z + s2 * bb2.z;
        r.w = acc[i][3] + bsv.w + s0 * bb0.w + s1 * bb1.w + s2 * bb2.w;
        const float kInvSqrt2 = 0.70710678118654752440f;
        r.x = 0.5f * r.x * (1.f + erff(r.x * kInvSqrt2));
        r.y = 0.5f * r.y * (1.f + erff(r.y * kInvSqrt2));
        r.z = 0.5f * r.z * (1.f + erff(r.z * kInvSqrt2));
        r.w = 0.5f * r.w * (1.f + erff(r.w * kInvSqrt2));
        *(float4*)(out + (size_t)node * D + jc) = r;
    }
}

// ================= PATH C: zero-workspace fallback =================
__global__ __launch_bounds__(256) void selfmv_kernel(
    const float* __restrict__ x, const float* __restrict__ Ws,
    const float* __restrict__ bs, const float* __restrict__ attn,
    float* __restrict__ out, int nN) {
    float a0 = attn[0], a1 = attn[1], a2 = attn[2], a3 = attn[3];
    float m = fmaxf(fmaxf(a0, a1), fmaxf(a2, a3));
    float e3 = expf(a3 - m);
    float inv = 1.f / (expf(a0 - m) + expf(a1 - m) + expf(a2 - m) + e3);
    float at3 = e3 * inv;
    int wave = (blockIdx.x * blockDim.x + threadIdx.x) >> 6;
    int lane = threadIdx.x & 63;
    int nw = (gridDim.x * blockDim.x) >> 6;
    for (int n = wave; n < nN; n += nw) {
        float2 xr = *(const float2*)(x + (size_t)n * D + lane * 2);
        float acc0 = 0.f, acc1 = 0.f;
#pragma unroll
        for (int k = 0; k < D; ++k) {
            float xv = __shfl((k & 1) ? xr.y : xr.x, k >> 1);
            float2 wv = *(const float2*)(Ws + (size_t)k * D + lane * 2);
            acc0 = fmaf(xv, wv.x, acc0);
            acc1 = fmaf(xv, wv.y, acc1);
        }
        float2 r;
        r.x = at3 * (acc0 + bs[lane * 2]);
        r.y = at3 * (acc1 + bs[lane * 2 + 1]);
        *(float2*)(out + (size_t)n * D + lane * 2) = r;
    }
}

__global__ __launch_bounds__(256) void edgemv_kernel(
    const float* __restrict__ x, const int* __restrict__ ei,
    const int* __restrict__ et, const float* __restrict__ ew,
    const float* __restrict__ We, const float* __restrict__ be,
    const float* __restrict__ attn, float* __restrict__ out, int nE) {
    float a0 = attn[0], a1 = attn[1], a2 = attn[2], a3 = attn[3];
    float m = fmaxf(fmaxf(a0, a1), fmaxf(a2, a3));
    float e0 = expf(a0 - m), e1 = expf(a1 - m), e2 = expf(a2 - m), e3 = expf(a3 - m);
    float inv = 1.f / (e0 + e1 + e2 + e3);
    float at[NT] = {e0 * inv, e1 * inv, e2 * inv};
    int wave = (blockIdx.x * blockDim.x + threadIdx.x) >> 6;
    int lane = threadIdx.x & 63;
    int nw = (gridDim.x * blockDim.x) >> 6;
    for (int e = wave; e < nE; e += nw) {
        int src = ei[e];
        int dst = ei[nE + e];
        int t = et[e];
        float sc = ew[e] * at[t];
        const float* W = We + (size_t)t * D * D;
        float2 xr = *(const float2*)(x + (size_t)src * D + lane * 2);
        float acc0 = 0.f, acc1 = 0.f;
#pragma unroll
        for (int k = 0; k < D; ++k) {
            float xv = __shfl((k & 1) ? xr.y : xr.x, k >> 1);
            float2 wv = *(const float2*)(W + (size_t)k * D + lane * 2);
            acc0 = fmaf(xv, wv.x, acc0);
            acc1 = fmaf(xv, wv.y, acc1);
        }
        float* p = out + (size_t)dst * D + lane * 2;
        unsafeAtomicAdd(p,     sc * (acc0 + be[(size_t)t * D + lane * 2]));
        unsafeAtomicAdd(p + 1, sc * (acc1 + be[(size_t)t * D + lane * 2 + 1]));
    }
}

__global__ void gelu_kernel(float* __restrict__ p, long long n4) {
    long long i = (long long)blockIdx.x * blockDim.x + threadIdx.x;
    long long stride = (long long)gridDim.x * blockDim.x;
    const float kInvSqrt2 = 0.70710678118654752440f;
    for (; i < n4; i += stride) {
        float4 r = ((float4*)p)[i];
        r.x = 0.5f * r.x * (1.f + erff(r.x * kInvSqrt2));
        r.y = 0.5f * r.y * (1.f + erff(r.y * kInvSqrt2));
        r.z = 0.5f * r.z * (1.f + erff(r.z * kInvSqrt2));
        r.w = 0.5f * r.w * (1.f + erff(r.w * kInvSqrt2));
        ((float4*)p)[i] = r;
    }
}

extern "C" void kernel_launch(void* const* d_in, const int* in_sizes, int n_in,
                              void* d_out, int out_size, void* d_ws, size_t ws_size,
                              hipStream_t stream) {
    const float* x = (const float*)d_in[0];
    const int* ei = (const int*)d_in[1];      // int64 in reference -> int32 here
    const int* et = (const int*)d_in[2];
    const float* ew = (const float*)d_in[3];
    const float* W_edge = (const float*)d_in[4];
    const float* b_edge = (const float*)d_in[5];
    const float* W_self = (const float*)d_in[6];
    const float* b_self = (const float*)d_in[7];
    const float* attention = (const float*)d_in[8];
    float* out = (float*)d_out;

    const int nN = in_sizes[0] / D;   // 100000
    const int nE = in_sizes[2];       // 600000
    const int nb = (nN + TM - 1) / TM;

    // ---- fused path workspace (16B-aligned sections) ----
    size_t off = 0;
    auto take = [&](size_t bytes) { size_t o = (off + 15) & ~(size_t)15; off = o + bytes; return o; };
    size_t o_wcat  = take((size_t)KTOT * D * 4);
    size_t o_biasb = take((size_t)KTOT * 4);
    size_t o_bfrag = take(131072);
    size_t o_bcnt  = take((size_t)(nb + 2) * 4);          // bcnt[nb] + ovfc[2]
    size_t o_ovfl  = take((size_t)nE * 4);
    size_t o_buck  = take((size_t)nb * BCAP * 8);
    size_t o_xb    = take((size_t)nN * D * 2);
    size_t needFused = off;

    if (ws_size >= needFused && nN < (1 << 20)) {
        char* ws = (char*)d_ws;
        float* wcat = (float*)(ws + o_wcat);
        float* biasb = (float*)(ws + o_biasb);
        unsigned short* bfrag = (unsigned short*)(ws + o_bfrag);
        int* bcnt = (int*)(ws + o_bcnt);
        int* ovfc = bcnt + nb;
        int* ovfl = (int*)(ws + o_ovfl);
        int2* bucket = (int2*)(ws + o_buck);
        unsigned short* xb = (unsigned short*)(ws + o_xb);

        hipLaunchKernelGGL(prep_kernel, dim3(64), dim3(256), 0, stream,
                           W_edge, b_edge, W_self, b_self, attention, wcat, biasb, bfrag,
                           bcnt, nb + 2);
        const int XB = 512;
        const int FB = (nE + 255) / 256;
        hipLaunchKernelGGL(xcvt_bin_kernel, dim3(XB + FB), dim3(256), 0, stream,
                           x, xb, nN, ei, et, ew, bcnt, bucket, ovfc, ovfl, nE, XB);
        hipLaunchKernelGGL(fusedB_kernel, dim3(nb), dim3(512), 0, stream,
                           xb, bucket, bcnt, bfrag, biasb, ei, et, ew, ovfc, ovfl, out, nN, nE);
        return;
    }

    const size_t baseFloats = (size_t)nN * NT * D + (size_t)nN * NT + (size_t)KTOT * D + KTOT;
    if (ws_size >= baseFloats * 4) {
        float* agg = (float*)d_ws;
        float* sW = agg + (size_t)nN * NT * D;
        float* wcat = sW + (size_t)nN * NT;
        float* biasb = wcat + (size_t)KTOT * D;
        long long zeroFloats = (long long)nN * (NT * D + NT);
        hipLaunchKernelGGL(zero_kernel, dim3(2048), dim3(256), 0, stream, agg, (zeroFloats + 3) / 4);
        hipLaunchKernelGGL(prep_kernel, dim3(64), dim3(256), 0, stream,
                           W_edge, b_edge, W_self, b_self, attention, wcat, biasb,
                           (unsigned short*)nullptr, (int*)nullptr, 0);
        hipLaunchKernelGGL(scatterA_kernel, dim3(2048), dim3(256), 0, stream,
                           x, ei, et, ew, agg, sW, nE);
        hipLaunchKernelGGL(gemm_gelu_kernel, dim3((nN + BM - 1) / BM), dim3(256), 0, stream,
                           x, agg, sW, wcat, biasb, out, nN);
    } else {
        hipLaunchKernelGGL(selfmv_kernel, dim3(2048), dim3(256), 0, stream,
                           x, W_self, b_self, attention, out, nN);
        hipLaunchKernelGGL(edgemv_kernel, dim3(2048), dim3(256), 0, stream,
                           x, ei, et, ew, W_edge, b_edge, attention, out, nE);
        hipLaunchKernelGGL(gelu_kernel, dim3(2048), dim3(256), 0, stream,
                           out, (long long)nN * D / 4);
    }
}

// Round 10
// 125.858 us; speedup vs baseline: 1.3330x; 1.3330x over previous
//
#include <hip/hip_runtime.h>
#include <hip/hip_bf16.h>
#include <math.h>

#define D 128
#define NT 3
#define KTOT (D * (NT + 1))   // 512
#define TM 32                 // nodes per fused block
#define NCAP 32               // per-node csr capacity

typedef __attribute__((ext_vector_type(8))) __bf16 bf16x8;
typedef __attribute__((ext_vector_type(4))) float f32x4;

__device__ inline unsigned short f2bf(float f) {
    unsigned int u = __float_as_uint(f);
    unsigned int r = (u + 0x7FFFu + ((u >> 16) & 1u)) >> 16;
    return (unsigned short)r;
}
__device__ inline float bf2f(unsigned int low16) {
    return __uint_as_float(low16 << 16);
}

// ---------------- zero helper (fallback path) ----------------
__global__ void zero_kernel(float* __restrict__ p, long long n4) {
    long long i = (long long)blockIdx.x * blockDim.x + threadIdx.x;
    long long stride = (long long)gridDim.x * blockDim.x;
    float4 z = make_float4(0.f, 0.f, 0.f, 0.f);
    for (; i < n4; i += stride) ((float4*)p)[i] = z;
}

// ---------------- prep: softmax(attention) -> wcat, biasb, bfrag; zero deg/ovfc ----------------
__global__ void prep_kernel(const float* __restrict__ W_edge, const float* __restrict__ b_edge,
                            const float* __restrict__ W_self, const float* __restrict__ b_self,
                            const float* __restrict__ attention,
                            float* __restrict__ wcat, float* __restrict__ biasb,
                            unsigned short* __restrict__ bfrag,
                            int* __restrict__ zeroMe, int zeroN) {
    float a0 = attention[0], a1 = attention[1], a2 = attention[2], a3 = attention[3];
    float m = fmaxf(fmaxf(a0, a1), fmaxf(a2, a3));
    float e0 = expf(a0 - m), e1 = expf(a1 - m), e2 = expf(a2 - m), e3 = expf(a3 - m);
    float inv = 1.f / (e0 + e1 + e2 + e3);
    float at[4] = {e0 * inv, e1 * inv, e2 * inv, e3 * inv};

    int idx0 = blockIdx.x * blockDim.x + threadIdx.x;
    int stride = gridDim.x * blockDim.x;
    if (zeroMe) {
        for (int i = idx0; i < zeroN; i += stride) zeroMe[i] = 0;
    }
    for (int i = idx0; i < KTOT * D; i += stride) {
        int k = i >> 7, j = i & (D - 1);
        float v;
        if (k < D) {
            v = at[NT] * W_self[k * D + j];
        } else {
            int t = (k - D) >> 7;
            int kk = (k - D) & (D - 1);
            v = at[t] * W_edge[(t * D + kk) * D + j];
        }
        wcat[i] = v;
    }
    for (int i = idx0; i < KTOT; i += stride) {
        if (i < NT * D) {
            int t = i >> 7, j = i & (D - 1);
            biasb[i] = at[t] * b_edge[t * D + j];
        } else {
            biasb[i] = at[NT] * b_self[i - NT * D];
        }
    }
    if (bfrag) {
        // bfrag: [(step*8+cf)*64+lane]*8 ; B[k][col], col=cf*16+(l&15), k=step*32+(l>>4)*8+j
        for (int i = idx0; i < 16 * 8 * 64; i += stride) {
            int l = i & 63;
            int cf = (i >> 6) & 7;
            int step = i >> 9;
            int col = cf * 16 + (l & 15);
            int kb = step * 32 + ((l >> 4) * 8);
#pragma unroll
            for (int j = 0; j < 8; ++j) {
                int k = kb + j;
                float v;
                if (k < D) {
                    v = at[NT] * W_self[k * D + col];
                } else {
                    int t = (k - D) >> 7;
                    int kk = (k - D) & (D - 1);
                    v = at[t] * W_edge[(t * D + kk) * D + col];
                }
                bfrag[(size_t)i * 8 + j] = f2bf(v);
            }
        }
    }
}

// ---------------- xcvt: f32 x -> bf16 xb (row stride D) ----------------
__global__ __launch_bounds__(256) void xcvt_kernel(
    const float* __restrict__ x, unsigned short* __restrict__ xb, int nN) {
    int i = blockIdx.x * blockDim.x + threadIdx.x;
    int total = nN * (D / 4);
    int stride = gridDim.x * blockDim.x;
    for (; i < total; i += stride) {
        int n = i >> 5;
        int c4 = (i & 31) * 4;
        float4 v = *(const float4*)(x + (size_t)n * D + c4);
        ushort4 o;
        o.x = f2bf(v.x); o.y = f2bf(v.y); o.z = f2bf(v.z); o.w = f2bf(v.w);
        *(ushort4*)(xb + (size_t)n * D + c4) = o;
    }
}

// ---------------- fill: bucket edges by dst into global csr ----------------
__global__ __launch_bounds__(256) void fill_kernel(
    const int* __restrict__ ei, const int* __restrict__ et, const float* __restrict__ ew,
    int* __restrict__ deg, int2* __restrict__ csr, int* __restrict__ ovfcnt,
    int* __restrict__ ovflist, int nE) {
    int e = blockIdx.x * blockDim.x + threadIdx.x;
    if (e >= nE) return;
    int dst = ei[nE + e];
    int pos = atomicAdd(deg + dst, 1);
    if (pos < NCAP) {
        int src = ei[e];
        int t = et[e];
        csr[(size_t)dst * NCAP + pos] = make_int2(src | (t << 20), __float_as_int(ew[e]));
    } else {
        int o = atomicAdd(ovfcnt, 1);
        ovflist[o] = e;
    }
}

// ---------------- fused gather + MFMA GEMM (round-8 structure, bf16 xb source) ----------------
// Block: 32 nodes, 512 threads (8 waves). LDS: A[32][64 chunks of 16B] (chunk XOR swizzle) @0
// (32KB); B dbuf 2x8KB @32768; s[32][3] f32 @49152. Total 49536 -> 3 blocks/CU.
__global__ __launch_bounds__(512, 6) void fused_gemm_kernel(
    const unsigned short* __restrict__ xb, const int2* __restrict__ csr,
    const int* __restrict__ deg, const unsigned short* __restrict__ bfrag,
    const float* __restrict__ biasb,
    const int* __restrict__ ei, const int* __restrict__ et, const float* __restrict__ ew,
    const int* __restrict__ ovfc, const int* __restrict__ ovfl,
    float* __restrict__ out, int nN, int nE) {
    __shared__ unsigned char lds[49536];
    float* sL = (float*)(lds + 49152);
    int t = threadIdx.x;
    int w = t >> 6;
    int lane = t & 63;
    int gl = lane & 15;
    int gbase = lane & 48;
    int row0 = blockIdx.x * TM;

#define BSTAGE(buf, st_) do {                                                                     \
        const unsigned short* gsrc = bfrag + (size_t)(st_) * 4096 + w * 512 + lane * 8;           \
        unsigned char* ldst = lds + 32768 + (buf) * 8192 + w * 1024;                              \
        __builtin_amdgcn_global_load_lds((const __attribute__((address_space(1))) void*)gsrc,     \
                                         (__attribute__((address_space(3))) void*)ldst, 16, 0, 0);\
    } while (0)

    BSTAGE(0, 0);   // overlaps the gather phase

    // ---------- gather phase: wave w owns nodes row0 + w*4 .. +3 (16 lanes/node) ----------
    int lrow = w * 4 + (lane >> 4);
    int node = row0 + lrow;
    int nclamp = (node < nN) ? node : (nN - 1);
    int dg = (node < nN) ? deg[nclamp] : 0;
    if (dg > NCAP) dg = NCAP;
    const int2* c = csr + (size_t)nclamp * NCAP;
    int2 mA = (gl < dg) ? c[gl] : make_int2(0, 0);
    int2 mB = (gl + 16 < dg) ? c[gl + 16] : make_int2(0, 0);

    float ac0[8], ac1[8], ac2[8];
#pragma unroll
    for (int j = 0; j < 8; ++j) { ac0[j] = 0.f; ac1[j] = 0.f; ac2[j] = 0.f; }
    float sw0 = 0.f, sw1 = 0.f, sw2 = 0.f;

    for (int i = 0; i < dg; i += 2) {
        int slA = gbase + (i & 15);
        int exA = __shfl((i < 16) ? mA.x : mB.x, slA);
        int ewA = __shfl((i < 16) ? mA.y : mB.y, slA);
        int srcA = exA & 0xFFFFF;
        if (srcA >= nN) srcA = 0;
        float wA = __int_as_float(ewA);
        int tA = (exA >> 20) & 3;
        bool actB = (i + 1 < dg);
        int slB = gbase + ((i + 1) & 15);
        int exB = __shfl((i + 1 < 16) ? mA.x : mB.x, slB);
        int ewB = __shfl((i + 1 < 16) ? mA.y : mB.y, slB);
        int srcB = exB & 0xFFFFF;
        if (!actB || srcB >= nN) srcB = 0;
        float wB = actB ? __int_as_float(ewB) : 0.f;
        int tB = (exB >> 20) & 3;

        uint4 xa = *(const uint4*)(xb + (size_t)srcA * D + gl * 8);
        uint4 xv = *(const uint4*)(xb + (size_t)srcB * D + gl * 8);

        float wA0 = (tA == 0) ? wA : 0.f;
        float wA1 = (tA == 1) ? wA : 0.f;
        float wA2 = (tA == 2) ? wA : 0.f;
        float wB0 = (tB == 0) ? wB : 0.f;
        float wB1 = (tB == 1) ? wB : 0.f;
        float wB2 = (tB == 2) ? wB : 0.f;
        sw0 += wA0 + wB0; sw1 += wA1 + wB1; sw2 += wA2 + wB2;

        float f0, f1;
#define ACCUM(u, j0, j1, w0_, w1_, w2_)                                   \
        f0 = __uint_as_float((u) << 16);                                  \
        f1 = __uint_as_float((u) & 0xFFFF0000u);                          \
        ac0[j0] = fmaf(w0_, f0, ac0[j0]); ac0[j1] = fmaf(w0_, f1, ac0[j1]); \
        ac1[j0] = fmaf(w1_, f0, ac1[j0]); ac1[j1] = fmaf(w1_, f1, ac1[j1]); \
        ac2[j0] = fmaf(w2_, f0, ac2[j0]); ac2[j1] = fmaf(w2_, f1, ac2[j1]);
        ACCUM(xa.x, 0, 1, wA0, wA1, wA2)
        ACCUM(xa.y, 2, 3, wA0, wA1, wA2)
        ACCUM(xa.z, 4, 5, wA0, wA1, wA2)
        ACCUM(xa.w, 6, 7, wA0, wA1, wA2)
        ACCUM(xv.x, 0, 1, wB0, wB1, wB2)
        ACCUM(xv.y, 2, 3, wB0, wB1, wB2)
        ACCUM(xv.z, 4, 5, wB0, wB1, wB2)
        ACCUM(xv.w, 6, 7, wB0, wB1, wB2)
#undef ACCUM
    }

    // ---- write A tile (chunk-XOR swizzled, both sides — rule #21) ----
    {
        int swz = lrow & 15;
        uint4 xo = *(const uint4*)(xb + (size_t)nclamp * D + gl * 8);   // own row, already bf16
        *(uint4*)(lds + lrow * 1024 + ((gl ^ swz) << 4)) = xo;
        uint4 o;
#define PACKST(arr, tt)                                                                \
        o.x = (unsigned int)f2bf(arr[0]) | ((unsigned int)f2bf(arr[1]) << 16);         \
        o.y = (unsigned int)f2bf(arr[2]) | ((unsigned int)f2bf(arr[3]) << 16);         \
        o.z = (unsigned int)f2bf(arr[4]) | ((unsigned int)f2bf(arr[5]) << 16);         \
        o.w = (unsigned int)f2bf(arr[6]) | ((unsigned int)f2bf(arr[7]) << 16);         \
        *(uint4*)(lds + lrow * 1024 + 256 + (tt) * 256 + ((gl ^ swz) << 4)) = o;
        PACKST(ac0, 0)
        PACKST(ac1, 1)
        PACKST(ac2, 2)
#undef PACKST
        if (gl < 3) {
            float sv = (gl == 0) ? sw0 : ((gl == 1) ? sw1 : sw2);
            sL[lrow * NT + gl] = sv;
        }
    }
    __syncthreads();

    // ---------- overflow patch (cnt == 0 in practice; correct for any data) ----------
    int cnt = *ovfc;
    if (cnt > 0) {
        if (w == 0 && lane < 16) {
            for (int i = 0; i < cnt; ++i) {
                int e = ovfl[i];
                int dst = ei[nE + e];
                if (dst >= row0 && dst < row0 + TM && dst < nN) {
                    int tt = et[e];
                    float wt = ew[e];
                    int src = ei[e];
                    int lr = dst - row0;
                    uint4* p = (uint4*)(lds + lr * 1024 + 256 + tt * 256 + ((lane ^ (lr & 15)) << 4));
                    uint4 cu = *p;
                    uint4 xr = *(const uint4*)(xb + (size_t)src * D + lane * 8);
                    float f0 = bf2f(cu.x & 0xFFFF) + wt * bf2f(xr.x & 0xFFFF);
                    float f1 = bf2f(cu.x >> 16)    + wt * bf2f(xr.x >> 16);
                    float f2 = bf2f(cu.y & 0xFFFF) + wt * bf2f(xr.y & 0xFFFF);
                    float f3 = bf2f(cu.y >> 16)    + wt * bf2f(xr.y >> 16);
                    float f4 = bf2f(cu.z & 0xFFFF) + wt * bf2f(xr.z & 0xFFFF);
                    float f5 = bf2f(cu.z >> 16)    + wt * bf2f(xr.z >> 16);
                    float f6 = bf2f(cu.w & 0xFFFF) + wt * bf2f(xr.w & 0xFFFF);
                    float f7 = bf2f(cu.w >> 16)    + wt * bf2f(xr.w >> 16);
                    cu.x = (unsigned int)f2bf(f0) | ((unsigned int)f2bf(f1) << 16);
                    cu.y = (unsigned int)f2bf(f2) | ((unsigned int)f2bf(f3) << 16);
                    cu.z = (unsigned int)f2bf(f4) | ((unsigned int)f2bf(f5) << 16);
                    cu.w = (unsigned int)f2bf(f6) | ((unsigned int)f2bf(f7) << 16);
                    *p = cu;
                    if (lane == 0) sL[lr * NT + tt] += wt;
                }
            }
        }
        __syncthreads();
    }

    // ---------- GEMM phase: 16 K-steps, wave w -> cols w*16..+15 ----------
    int ll = lane & 15;
    int ck = lane >> 4;
    f32x4 acc0 = (f32x4){0.f, 0.f, 0.f, 0.f};
    f32x4 acc1 = (f32x4){0.f, 0.f, 0.f, 0.f};
#pragma unroll 2
    for (int st = 0; st < 16; ++st) {
        int cur = st & 1;
        if (st < 15) BSTAGE(cur ^ 1, st + 1);
        int cc = st * 4 + ck;
        int phys = (cc & 48) | ((cc & 15) ^ ll);
        bf16x8 a0 = *(const bf16x8*)(lds + ll * 1024 + (phys << 4));
        bf16x8 a1 = *(const bf16x8*)(lds + (16 + ll) * 1024 + (phys << 4));
        bf16x8 b = *(const bf16x8*)(lds + 32768 + cur * 8192 + ((w * 64 + lane) << 4));
        acc0 = __builtin_amdgcn_mfma_f32_16x16x32_bf16(a0, b, acc0, 0, 0, 0);
        acc1 = __builtin_amdgcn_mfma_f32_16x16x32_bf16(a1, b, acc1, 0, 0, 0);
        __syncthreads();
    }
#undef BSTAGE

    // ---------- epilogue ----------
    int colb = w * 16 + ll;
    float bb0 = biasb[colb], bb1 = biasb[D + colb], bb2 = biasb[2 * D + colb], bs4 = biasb[3 * D + colb];
    const float kInvSqrt2 = 0.70710678118654752440f;
#pragma unroll
    for (int fr = 0; fr < 2; ++fr) {
        f32x4 A = fr ? acc1 : acc0;
#pragma unroll
        for (int reg = 0; reg < 4; ++reg) {
            int lr = fr * 16 + ck * 4 + reg;
            long row = (long)row0 + lr;
            if (row >= nN) continue;
            float s0 = sL[lr * NT + 0];
            float s1 = sL[lr * NT + 1];
            float s2 = sL[lr * NT + 2];
            float v = A[reg] + bs4 + s0 * bb0 + s1 * bb1 + s2 * bb2;
            v = 0.5f * v * (1.f + erff(v * kInvSqrt2));
            out[row * D + colb] = v;
        }
    }
}

// ================= FALLBACK PATH (small ws): f32 atomic scatter + f32 GEMM =================
__global__ __launch_bounds__(256) void scatterA_kernel(
    const float* __restrict__ x, const int* __restrict__ ei,
    const int* __restrict__ et, const float* __restrict__ ew,
    float* __restrict__ agg, float* __restrict__ s, int nE) {
    int gtid = blockIdx.x * blockDim.x + threadIdx.x;
    int wave = gtid >> 6;
    int lane = threadIdx.x & 63;
    int nw = (gridDim.x * blockDim.x) >> 6;
    for (int e = wave; e < nE; e += nw) {
        int src = ei[e];
        int dst = ei[nE + e];
        int t = et[e];
        float w = ew[e];
        float2 xv = *(const float2*)(x + (size_t)src * D + lane * 2);
        float* p = agg + (size_t)dst * (NT * D) + t * D + lane * 2;
        unsafeAtomicAdd(p, w * xv.x);
        unsafeAtomicAdd(p + 1, w * xv.y);
        if (lane == 0) unsafeAtomicAdd(s + (size_t)dst * NT + t, w);
    }
}

#define BM 64
#define BK 32
__global__ __launch_bounds__(256) void gemm_gelu_kernel(
    const float* __restrict__ x, const float* __restrict__ agg,
    const float* __restrict__ s, const float* __restrict__ wcat,
    const float* __restrict__ biasb, float* __restrict__ out, int nNodes) {
    __shared__ float As[BK][BM + 1];
    __shared__ float Bs[BK][D];

    int tx = threadIdx.x;
    int row0 = blockIdx.x * BM;
    int cg = tx & 31;
    int rg = tx >> 5;
    int lr = tx >> 3;
    int lc = (tx & 7) * 4;

    float acc[8][4];
#pragma unroll
    for (int i = 0; i < 8; ++i)
#pragma unroll
        for (int j = 0; j < 4; ++j) acc[i][j] = 0.f;

    for (int k0 = 0; k0 < KTOT; k0 += BK) {
        const float* srcBase;
        int strideA, koff;
        if (k0 < D) { srcBase = x; strideA = D; koff = k0; }
        else        { srcBase = agg; strideA = NT * D; koff = k0 - D; }
#pragma unroll
        for (int h = 0; h < 2; ++h) {
            int r = lr + h * 32;
            int node = row0 + r;
            if (node >= nNodes) node = nNodes - 1;
            float4 v = *(const float4*)(srcBase + (size_t)node * strideA + koff + lc);
            As[lc + 0][r] = v.x; As[lc + 1][r] = v.y;
            As[lc + 2][r] = v.z; As[lc + 3][r] = v.w;
        }
        {
            int br = tx >> 5;
            int bc = (tx & 31) * 4;
#pragma unroll
            for (int h = 0; h < 4; ++h) {
                int r = br + h * 8;
                *(float4*)(&Bs[r][bc]) = *(const float4*)(wcat + (size_t)(k0 + r) * D + bc);
            }
        }
        __syncthreads();
#pragma unroll
        for (int kk = 0; kk < BK; ++kk) {
            float4 b = *(const float4*)(&Bs[kk][cg * 4]);
            float a[8];
            *(float4*)(a)     = *(const float4*)(&As[kk][rg * 8]);
            *(float4*)(a + 4) = *(const float4*)(&As[kk][rg * 8 + 4]);
#pragma unroll
            for (int i = 0; i < 8; ++i) {
                acc[i][0] = fmaf(a[i], b.x, acc[i][0]);
                acc[i][1] = fmaf(a[i], b.y, acc[i][1]);
                acc[i][2] = fmaf(a[i], b.z, acc[i][2]);
                acc[i][3] = fmaf(a[i], b.w, acc[i][3]);
            }
        }
        __syncthreads();
    }

    int jc = cg * 4;
    float4 bb0 = *(const float4*)(biasb + 0 * D + jc);
    float4 bb1 = *(const float4*)(biasb + 1 * D + jc);
    float4 bb2 = *(const float4*)(biasb + 2 * D + jc);
    float4 bsv = *(const float4*)(biasb + NT * D + jc);
#pragma unroll
    for (int i = 0; i < 8; ++i) {
        int node = row0 + rg * 8 + i;
        if (node >= nNodes) break;
        float s0 = s[(size_t)node * NT + 0];
        float s1 = s[(size_t)node * NT + 1];
        float s2 = s[(size_t)node * NT + 2];
        float4 r;
        r.x = acc[i][0] + bsv.x + s0 * bb0.x + s1 * bb1.x + s2 * bb2.x;
        r.y = acc[i][1] + bsv.y + s0 * bb0.y + s1 * bb1.y + s2 * bb2.y;
        r.z = acc[i][2] + bsv.z + s0 * bb0.z + s1 * bb1.z + s2 * bb2.z;
        r.w = acc[i][3] + bsv.w + s0 * bb0.w + s1 * bb1.w + s2 * bb2.w;
        const float kInvSqrt2 = 0.70710678118654752440f;
        r.x = 0.5f * r.x * (1.f + erff(r.x * kInvSqrt2));
        r.y = 0.5f * r.y * (1.f + erff(r.y * kInvSqrt2));
        r.z = 0.5f * r.z * (1.f + erff(r.z * kInvSqrt2));
        r.w = 0.5f * r.w * (1.f + erff(r.w * kInvSqrt2));
        *(float4*)(out + (size_t)node * D + jc) = r;
    }
}

// ================= PATH C: zero-workspace fallback =================
__global__ __launch_bounds__(256) void selfmv_kernel(
    const float* __restrict__ x, const float* __restrict__ Ws,
    const float* __restrict__ bs, const float* __restrict__ attn,
    float* __restrict__ out, int nN) {
    float a0 = attn[0], a1 = attn[1], a2 = attn[2], a3 = attn[3];
    float m = fmaxf(fmaxf(a0, a1), fmaxf(a2, a3));
    float e3 = expf(a3 - m);
    float inv = 1.f / (expf(a0 - m) + expf(a1 - m) + expf(a2 - m) + e3);
    float at3 = e3 * inv;
    int wave = (blockIdx.x * blockDim.x + threadIdx.x) >> 6;
    int lane = threadIdx.x & 63;
    int nw = (gridDim.x * blockDim.x) >> 6;
    for (int n = wave; n < nN; n += nw) {
        float2 xr = *(const float2*)(x + (size_t)n * D + lane * 2);
        float acc0 = 0.f, acc1 = 0.f;
#pragma unroll
        for (int k = 0; k < D; ++k) {
            float xv = __shfl((k & 1) ? xr.y : xr.x, k >> 1);
            float2 wv = *(const float2*)(Ws + (size_t)k * D + lane * 2);
            acc0 = fmaf(xv, wv.x, acc0);
            acc1 = fmaf(xv, wv.y, acc1);
        }
        float2 r;
        r.x = at3 * (acc0 + bs[lane * 2]);
        r.y = at3 * (acc1 + bs[lane * 2 + 1]);
        *(float2*)(out + (size_t)n * D + lane * 2) = r;
    }
}

__global__ __launch_bounds__(256) void edgemv_kernel(
    const float* __restrict__ x, const int* __restrict__ ei,
    const int* __restrict__ et, const float* __restrict__ ew,
    const float* __restrict__ We, const float* __restrict__ be,
    const float* __restrict__ attn, float* __restrict__ out, int nE) {
    float a0 = attn[0], a1 = attn[1], a2 = attn[2], a3 = attn[3];
    float m = fmaxf(fmaxf(a0, a1), fmaxf(a2, a3));
    float e0 = expf(a0 - m), e1 = expf(a1 - m), e2 = expf(a2 - m), e3 = expf(a3 - m);
    float inv = 1.f / (e0 + e1 + e2 + e3);
    float at[NT] = {e0 * inv, e1 * inv, e2 * inv};
    int wave = (blockIdx.x * blockDim.x + threadIdx.x) >> 6;
    int lane = threadIdx.x & 63;
    int nw = (gridDim.x * blockDim.x) >> 6;
    for (int e = wave; e < nE; e += nw) {
        int src = ei[e];
        int dst = ei[nE + e];
        int t = et[e];
        float sc = ew[e] * at[t];
        const float* W = We + (size_t)t * D * D;
        float2 xr = *(const float2*)(x + (size_t)src * D + lane * 2);
        float acc0 = 0.f, acc1 = 0.f;
#pragma unroll
        for (int k = 0; k < D; ++k) {
            float xv = __shfl((k & 1) ? xr.y : xr.x, k >> 1);
            float2 wv = *(const float2*)(W + (size_t)k * D + lane * 2);
            acc0 = fmaf(xv, wv.x, acc0);
            acc1 = fmaf(xv, wv.y, acc1);
        }
        float* p = out + (size_t)dst * D + lane * 2;
        unsafeAtomicAdd(p,     sc * (acc0 + be[(size_t)t * D + lane * 2]));
        unsafeAtomicAdd(p + 1, sc * (acc1 + be[(size_t)t * D + lane * 2 + 1]));
    }
}

__global__ void gelu_kernel(float* __restrict__ p, long long n4) {
    long long i = (long long)blockIdx.x * blockDim.x + threadIdx.x;
    long long stride = (long long)gridDim.x * blockDim.x;
    const float kInvSqrt2 = 0.70710678118654752440f;
    for (; i < n4; i += stride) {
        float4 r = ((float4*)p)[i];
        r.x = 0.5f * r.x * (1.f + erff(r.x * kInvSqrt2));
        r.y = 0.5f * r.y * (1.f + erff(r.y * kInvSqrt2));
        r.z = 0.5f * r.z * (1.f + erff(r.z * kInvSqrt2));
        r.w = 0.5f * r.w * (1.f + erff(r.w * kInvSqrt2));
        ((float4*)p)[i] = r;
    }
}

extern "C" void kernel_launch(void* const* d_in, const int* in_sizes, int n_in,
                              void* d_out, int out_size, void* d_ws, size_t ws_size,
                              hipStream_t stream) {
    const float* x = (const float*)d_in[0];
    const int* ei = (const int*)d_in[1];      // int64 in reference -> int32 here
    const int* et = (const int*)d_in[2];
    const float* ew = (const float*)d_in[3];
    const float* W_edge = (const float*)d_in[4];
    const float* b_edge = (const float*)d_in[5];
    const float* W_self = (const float*)d_in[6];
    const float* b_self = (const float*)d_in[7];
    const float* attention = (const float*)d_in[8];
    float* out = (float*)d_out;

    const int nN = in_sizes[0] / D;   // 100000
    const int nE = in_sizes[2];       // 600000

    // ---- fused path workspace (16B-aligned sections) ----
    size_t off = 0;
    auto take = [&](size_t bytes) { size_t o = (off + 15) & ~(size_t)15; off = o + bytes; return o; };
    size_t o_wcat  = take((size_t)KTOT * D * 4);
    size_t o_biasb = take((size_t)KTOT * 4);
    size_t o_bfrag = take(131072);
    size_t o_deg   = take((size_t)(nN + 2) * 4);          // deg[nN] + ovfc
    size_t o_ovfl  = take((size_t)nE * 4);
    size_t o_csr   = take((size_t)nN * NCAP * 8);
    size_t o_xb    = take((size_t)nN * D * 2);
    size_t needFused = off;

    if (ws_size >= needFused && nN < (1 << 20)) {
        char* ws = (char*)d_ws;
        float* wcat = (float*)(ws + o_wcat);
        float* biasb = (float*)(ws + o_biasb);
        unsigned short* bfrag = (unsigned short*)(ws + o_bfrag);
        int* deg = (int*)(ws + o_deg);
        int* ovfc = deg + nN;
        int* ovfl = (int*)(ws + o_ovfl);
        int2* csr = (int2*)(ws + o_csr);
        unsigned short* xb = (unsigned short*)(ws + o_xb);

        hipLaunchKernelGGL(prep_kernel, dim3(64), dim3(256), 0, stream,
                           W_edge, b_edge, W_self, b_self, attention, wcat, biasb, bfrag,
                           deg, nN + 2);
        hipLaunchKernelGGL(xcvt_kernel, dim3(2048), dim3(256), 0, stream, x, xb, nN);
        hipLaunchKernelGGL(fill_kernel, dim3((nE + 255) / 256), dim3(256), 0, stream,
                           ei, et, ew, deg, csr, ovfc, ovfl, nE);
        hipLaunchKernelGGL(fused_gemm_kernel, dim3((nN + TM - 1) / TM), dim3(512), 0, stream,
                           xb, csr, deg, bfrag, biasb, ei, et, ew, ovfc, ovfl, out, nN, nE);
        return;
    }

    const size_t baseFloats = (size_t)nN * NT * D + (size_t)nN * NT + (size_t)KTOT * D + KTOT;
    if (ws_size >= baseFloats * 4) {
        float* agg = (float*)d_ws;
        float* sW = agg + (size_t)nN * NT * D;
        float* wcat = sW + (size_t)nN * NT;
        float* biasb = wcat + (size_t)KTOT * D;
        long long zeroFloats = (long long)nN * (NT * D + NT);
        hipLaunchKernelGGL(zero_kernel, dim3(2048), dim3(256), 0, stream, agg, (zeroFloats + 3) / 4);
        hipLaunchKernelGGL(prep_kernel, dim3(64), dim3(256), 0, stream,
                           W_edge, b_edge, W_self, b_self, attention, wcat, biasb,
                           (unsigned short*)nullptr, (int*)nullptr, 0);
        hipLaunchKernelGGL(scatterA_kernel, dim3(2048), dim3(256), 0, stream,
                           x, ei, et, ew, agg, sW, nE);
        hipLaunchKernelGGL(gemm_gelu_kernel, dim3((nN + BM - 1) / BM), dim3(256), 0, stream,
                           x, agg, sW, wcat, biasb, out, nN);
    } else {
        hipLaunchKernelGGL(selfmv_kernel, dim3(2048), dim3(256), 0, stream,
                           x, W_self, b_self, attention, out, nN);
        hipLaunchKernelGGL(edgemv_kernel, dim3(2048), dim3(256), 0, stream,
                           x, ei, et, ew, W_edge, b_edge, attention, out, nE);
        hipLaunchKernelGGL(gelu_kernel, dim3(2048), dim3(256), 0, stream,
                           out, (long long)nN * D / 4);
    }
}

// Round 11
// 117.368 us; speedup vs baseline: 1.4294x; 1.0723x over previous
//
#include <hip/hip_runtime.h>
#include <hip/hip_bf16.h>
#include <math.h>

#define D 128
#define NT 3
#define KTOT (D * (NT + 1))   // 512
#define TM 32                 // nodes per fused block
#define NCAP 32               // per-node csr capacity

typedef __attribute__((ext_vector_type(8))) __bf16 bf16x8;
typedef __attribute__((ext_vector_type(4))) float f32x4;

__device__ inline unsigned short f2bf(float f) {
    unsigned int u = __float_as_uint(f);
    unsigned int r = (u + 0x7FFFu + ((u >> 16) & 1u)) >> 16;
    return (unsigned short)r;
}
__device__ inline float bf2f(unsigned int low16) {
    return __uint_as_float(low16 << 16);
}

// ---------------- zero helper (fallback path) ----------------
__global__ void zero_kernel(float* __restrict__ p, long long n4) {
    long long i = (long long)blockIdx.x * blockDim.x + threadIdx.x;
    long long stride = (long long)gridDim.x * blockDim.x;
    float4 z = make_float4(0.f, 0.f, 0.f, 0.f);
    for (; i < n4; i += stride) ((float4*)p)[i] = z;
}

// ---------------- prep: softmax(attention) -> wcat, biasb, bfrag; zero deg/ovfc ----------------
__global__ void prep_kernel(const float* __restrict__ W_edge, const float* __restrict__ b_edge,
                            const float* __restrict__ W_self, const float* __restrict__ b_self,
                            const float* __restrict__ attention,
                            float* __restrict__ wcat, float* __restrict__ biasb,
                            unsigned short* __restrict__ bfrag,
                            int* __restrict__ zeroMe, int zeroN) {
    float a0 = attention[0], a1 = attention[1], a2 = attention[2], a3 = attention[3];
    float m = fmaxf(fmaxf(a0, a1), fmaxf(a2, a3));
    float e0 = expf(a0 - m), e1 = expf(a1 - m), e2 = expf(a2 - m), e3 = expf(a3 - m);
    float inv = 1.f / (e0 + e1 + e2 + e3);
    float at[4] = {e0 * inv, e1 * inv, e2 * inv, e3 * inv};

    int idx0 = blockIdx.x * blockDim.x + threadIdx.x;
    int stride = gridDim.x * blockDim.x;
    if (zeroMe) {
        for (int i = idx0; i < zeroN; i += stride) zeroMe[i] = 0;
    }
    for (int i = idx0; i < KTOT * D; i += stride) {
        int k = i >> 7, j = i & (D - 1);
        float v;
        if (k < D) {
            v = at[NT] * W_self[k * D + j];
        } else {
            int t = (k - D) >> 7;
            int kk = (k - D) & (D - 1);
            v = at[t] * W_edge[(t * D + kk) * D + j];
        }
        wcat[i] = v;
    }
    for (int i = idx0; i < KTOT; i += stride) {
        if (i < NT * D) {
            int t = i >> 7, j = i & (D - 1);
            biasb[i] = at[t] * b_edge[t * D + j];
        } else {
            biasb[i] = at[NT] * b_self[i - NT * D];
        }
    }
    if (bfrag) {
        // bfrag: [(step*8+cf)*64+lane]*8 ; B[k][col], col=cf*16+(l&15), k=step*32+(l>>4)*8+j
        for (int i = idx0; i < 16 * 8 * 64; i += stride) {
            int l = i & 63;
            int cf = (i >> 6) & 7;
            int step = i >> 9;
            int col = cf * 16 + (l & 15);
            int kb = step * 32 + ((l >> 4) * 8);
#pragma unroll
            for (int j = 0; j < 8; ++j) {
                int k = kb + j;
                float v;
                if (k < D) {
                    v = at[NT] * W_self[k * D + col];
                } else {
                    int t = (k - D) >> 7;
                    int kk = (k - D) & (D - 1);
                    v = at[t] * W_edge[(t * D + kk) * D + col];
                }
                bfrag[(size_t)i * 8 + j] = f2bf(v);
            }
        }
    }
}

// ---------------- merged per-thread: 1 edge fill + grid-strided x->bf16 ----------------
// Streaming conversions hide the random edge-atomic latency within each wave.
__global__ __launch_bounds__(256) void xcvt_fill_kernel(
    const float* __restrict__ x, unsigned short* __restrict__ xb, int nN,
    const int* __restrict__ ei, const int* __restrict__ et, const float* __restrict__ ew,
    int* __restrict__ deg, int2* __restrict__ csr, int* __restrict__ ovfcnt,
    int* __restrict__ ovflist, int nE) {
    int e = blockIdx.x * blockDim.x + threadIdx.x;

    // issue edge loads early
    int dst = 0, src = 0, t = 0;
    float w = 0.f;
    bool act = (e < nE);
    if (act) {
        dst = ei[nE + e];
        src = ei[e];
        t = et[e];
        w = ew[e];
    }

    // streaming xcvt (hides edge-load latency)
    int total = nN * (D / 4);
    int stride = gridDim.x * blockDim.x;
    for (int i = e; i < total; i += stride) {
        int n = i >> 5;
        int c4 = (i & 31) * 4;
        float4 v = *(const float4*)(x + (size_t)n * D + c4);
        ushort4 o;
        o.x = f2bf(v.x); o.y = f2bf(v.y); o.z = f2bf(v.z); o.w = f2bf(v.w);
        *(ushort4*)(xb + (size_t)n * D + c4) = o;
    }

    // edge bucketing
    if (act) {
        int pos = atomicAdd(deg + dst, 1);
        if (pos < NCAP) {
            csr[(size_t)dst * NCAP + pos] = make_int2(src | (t << 20), __float_as_int(w));
        } else {
            int o = atomicAdd(ovfcnt, 1);
            ovflist[o] = e;
        }
    }
}

// ---------------- fused gather + MFMA GEMM (barrier-free GEMM phase) ----------------
// Block: 32 nodes, 512 threads (8 waves). LDS: A[32][64 chunks of 16B] (chunk XOR swizzle) @0
// (32KB); s[32][3] f32 @32768. Total 33152 -> 4 blocks/CU (32 waves/CU).
// B fragments are register-loaded from L2-hot bfrag (128KB) -> no B staging, no GEMM barriers.
__global__ __launch_bounds__(512, 8) void fused_gemm_kernel(
    const unsigned short* __restrict__ xb, const int2* __restrict__ csr,
    const int* __restrict__ deg, const unsigned short* __restrict__ bfrag,
    const float* __restrict__ biasb,
    const int* __restrict__ ei, const int* __restrict__ et, const float* __restrict__ ew,
    const int* __restrict__ ovfc, const int* __restrict__ ovfl,
    float* __restrict__ out, int nN, int nE) {
    __shared__ unsigned char lds[33152];
    float* sL = (float*)(lds + 32768);
    int t = threadIdx.x;
    int w = t >> 6;
    int lane = t & 63;
    int gl = lane & 15;
    int gbase = lane & 48;
    int row0 = blockIdx.x * TM;

    // ---------- gather phase: wave w owns nodes row0 + w*4 .. +3 (16 lanes/node) ----------
    int lrow = w * 4 + (lane >> 4);
    int node = row0 + lrow;
    int nclamp = (node < nN) ? node : (nN - 1);
    int dg = (node < nN) ? deg[nclamp] : 0;
    if (dg > NCAP) dg = NCAP;
    const int2* c = csr + (size_t)nclamp * NCAP;
    int2 mA = (gl < dg) ? c[gl] : make_int2(0, 0);
    int2 mB = (gl + 16 < dg) ? c[gl + 16] : make_int2(0, 0);

    float ac0[8], ac1[8], ac2[8];
#pragma unroll
    for (int j = 0; j < 8; ++j) { ac0[j] = 0.f; ac1[j] = 0.f; ac2[j] = 0.f; }
    float sw0 = 0.f, sw1 = 0.f, sw2 = 0.f;

    for (int i = 0; i < dg; i += 2) {
        int slA = gbase + (i & 15);
        int exA = __shfl((i < 16) ? mA.x : mB.x, slA);
        int ewA = __shfl((i < 16) ? mA.y : mB.y, slA);
        int srcA = exA & 0xFFFFF;
        if (srcA >= nN) srcA = 0;
        float wA = __int_as_float(ewA);
        int tA = (exA >> 20) & 3;
        bool actB = (i + 1 < dg);
        int slB = gbase + ((i + 1) & 15);
        int exB = __shfl((i + 1 < 16) ? mA.x : mB.x, slB);
        int ewB = __shfl((i + 1 < 16) ? mA.y : mB.y, slB);
        int srcB = exB & 0xFFFFF;
        if (!actB || srcB >= nN) srcB = 0;
        float wB = actB ? __int_as_float(ewB) : 0.f;
        int tB = (exB >> 20) & 3;

        uint4 xa = *(const uint4*)(xb + (size_t)srcA * D + gl * 8);
        uint4 xv = *(const uint4*)(xb + (size_t)srcB * D + gl * 8);

        float wA0 = (tA == 0) ? wA : 0.f;
        float wA1 = (tA == 1) ? wA : 0.f;
        float wA2 = (tA == 2) ? wA : 0.f;
        float wB0 = (tB == 0) ? wB : 0.f;
        float wB1 = (tB == 1) ? wB : 0.f;
        float wB2 = (tB == 2) ? wB : 0.f;
        sw0 += wA0 + wB0; sw1 += wA1 + wB1; sw2 += wA2 + wB2;

        float f0, f1;
#define ACCUM(u, j0, j1, w0_, w1_, w2_)                                   \
        f0 = __uint_as_float((u) << 16);                                  \
        f1 = __uint_as_float((u) & 0xFFFF0000u);                          \
        ac0[j0] = fmaf(w0_, f0, ac0[j0]); ac0[j1] = fmaf(w0_, f1, ac0[j1]); \
        ac1[j0] = fmaf(w1_, f0, ac1[j0]); ac1[j1] = fmaf(w1_, f1, ac1[j1]); \
        ac2[j0] = fmaf(w2_, f0, ac2[j0]); ac2[j1] = fmaf(w2_, f1, ac2[j1]);
        ACCUM(xa.x, 0, 1, wA0, wA1, wA2)
        ACCUM(xa.y, 2, 3, wA0, wA1, wA2)
        ACCUM(xa.z, 4, 5, wA0, wA1, wA2)
        ACCUM(xa.w, 6, 7, wA0, wA1, wA2)
        ACCUM(xv.x, 0, 1, wB0, wB1, wB2)
        ACCUM(xv.y, 2, 3, wB0, wB1, wB2)
        ACCUM(xv.z, 4, 5, wB0, wB1, wB2)
        ACCUM(xv.w, 6, 7, wB0, wB1, wB2)
#undef ACCUM
    }

    // ---- write A tile (chunk-XOR swizzled, both sides — rule #21) ----
    {
        int swz = lrow & 15;
        uint4 xo = *(const uint4*)(xb + (size_t)nclamp * D + gl * 8);   // own row, already bf16
        *(uint4*)(lds + lrow * 1024 + ((gl ^ swz) << 4)) = xo;
        uint4 o;
#define PACKST(arr, tt)                                                                \
        o.x = (unsigned int)f2bf(arr[0]) | ((unsigned int)f2bf(arr[1]) << 16);         \
        o.y = (unsigned int)f2bf(arr[2]) | ((unsigned int)f2bf(arr[3]) << 16);         \
        o.z = (unsigned int)f2bf(arr[4]) | ((unsigned int)f2bf(arr[5]) << 16);         \
        o.w = (unsigned int)f2bf(arr[6]) | ((unsigned int)f2bf(arr[7]) << 16);         \
        *(uint4*)(lds + lrow * 1024 + 256 + (tt) * 256 + ((gl ^ swz) << 4)) = o;
        PACKST(ac0, 0)
        PACKST(ac1, 1)
        PACKST(ac2, 2)
#undef PACKST
        if (gl < 3) {
            float sv = (gl == 0) ? sw0 : ((gl == 1) ? sw1 : sw2);
            sL[lrow * NT + gl] = sv;
        }
    }
    __syncthreads();

    // ---------- overflow patch (cnt == 0 in practice; correct for any data) ----------
    int cnt = *ovfc;
    if (cnt > 0) {
        if (w == 0 && lane < 16) {
            for (int i = 0; i < cnt; ++i) {
                int e = ovfl[i];
                int dst = ei[nE + e];
                if (dst >= row0 && dst < row0 + TM && dst < nN) {
                    int tt = et[e];
                    float wt = ew[e];
                    int src = ei[e];
                    int lr = dst - row0;
                    uint4* p = (uint4*)(lds + lr * 1024 + 256 + tt * 256 + ((lane ^ (lr & 15)) << 4));
                    uint4 cu = *p;
                    uint4 xr = *(const uint4*)(xb + (size_t)src * D + lane * 8);
                    float f0 = bf2f(cu.x & 0xFFFF) + wt * bf2f(xr.x & 0xFFFF);
                    float f1 = bf2f(cu.x >> 16)    + wt * bf2f(xr.x >> 16);
                    float f2 = bf2f(cu.y & 0xFFFF) + wt * bf2f(xr.y & 0xFFFF);
                    float f3 = bf2f(cu.y >> 16)    + wt * bf2f(xr.y >> 16);
                    float f4 = bf2f(cu.z & 0xFFFF) + wt * bf2f(xr.z & 0xFFFF);
                    float f5 = bf2f(cu.z >> 16)    + wt * bf2f(xr.z >> 16);
                    float f6 = bf2f(cu.w & 0xFFFF) + wt * bf2f(xr.w & 0xFFFF);
                    float f7 = bf2f(cu.w >> 16)    + wt * bf2f(xr.w >> 16);
                    cu.x = (unsigned int)f2bf(f0) | ((unsigned int)f2bf(f1) << 16);
                    cu.y = (unsigned int)f2bf(f2) | ((unsigned int)f2bf(f3) << 16);
                    cu.z = (unsigned int)f2bf(f4) | ((unsigned int)f2bf(f5) << 16);
                    cu.w = (unsigned int)f2bf(f6) | ((unsigned int)f2bf(f7) << 16);
                    *p = cu;
                    if (lane == 0) sL[lr * NT + tt] += wt;
                }
            }
        }
        __syncthreads();
    }

    // ---------- GEMM phase: 16 K-steps, wave w -> cols w*16..+15, NO barriers ----------
    // B fragment register-loaded from L2-hot bfrag: step stride 4096 shorts, cf (=w) stride 512.
    int ll = lane & 15;
    int ck = lane >> 4;
    f32x4 acc0 = (f32x4){0.f, 0.f, 0.f, 0.f};
    f32x4 acc1 = (f32x4){0.f, 0.f, 0.f, 0.f};
#pragma unroll 4
    for (int st = 0; st < 16; ++st) {
        bf16x8 b = *(const bf16x8*)(bfrag + (size_t)st * 4096 + w * 512 + lane * 8);
        int cc = st * 4 + ck;
        int phys = (cc & 48) | ((cc & 15) ^ ll);
        bf16x8 a0 = *(const bf16x8*)(lds + ll * 1024 + (phys << 4));
        bf16x8 a1 = *(const bf16x8*)(lds + (16 + ll) * 1024 + (phys << 4));
        acc0 = __builtin_amdgcn_mfma_f32_16x16x32_bf16(a0, b, acc0, 0, 0, 0);
        acc1 = __builtin_amdgcn_mfma_f32_16x16x32_bf16(a1, b, acc1, 0, 0, 0);
    }

    // ---------- epilogue ----------
    int colb = w * 16 + ll;
    float bb0 = biasb[colb], bb1 = biasb[D + colb], bb2 = biasb[2 * D + colb], bs4 = biasb[3 * D + colb];
    const float kInvSqrt2 = 0.70710678118654752440f;
#pragma unroll
    for (int fr = 0; fr < 2; ++fr) {
        f32x4 A = fr ? acc1 : acc0;
#pragma unroll
        for (int reg = 0; reg < 4; ++reg) {
            int lr = fr * 16 + ck * 4 + reg;
            long row = (long)row0 + lr;
            if (row >= nN) continue;
            float s0 = sL[lr * NT + 0];
            float s1 = sL[lr * NT + 1];
            float s2 = sL[lr * NT + 2];
            float v = A[reg] + bs4 + s0 * bb0 + s1 * bb1 + s2 * bb2;
            v = 0.5f * v * (1.f + erff(v * kInvSqrt2));
            out[row * D + colb] = v;
        }
    }
}

// ================= FALLBACK PATH (small ws): f32 atomic scatter + f32 GEMM =================
__global__ __launch_bounds__(256) void scatterA_kernel(
    const float* __restrict__ x, const int* __restrict__ ei,
    const int* __restrict__ et, const float* __restrict__ ew,
    float* __restrict__ agg, float* __restrict__ s, int nE) {
    int gtid = blockIdx.x * blockDim.x + threadIdx.x;
    int wave = gtid >> 6;
    int lane = threadIdx.x & 63;
    int nw = (gridDim.x * blockDim.x) >> 6;
    for (int e = wave; e < nE; e += nw) {
        int src = ei[e];
        int dst = ei[nE + e];
        int t = et[e];
        float w = ew[e];
        float2 xv = *(const float2*)(x + (size_t)src * D + lane * 2);
        float* p = agg + (size_t)dst * (NT * D) + t * D + lane * 2;
        unsafeAtomicAdd(p, w * xv.x);
        unsafeAtomicAdd(p + 1, w * xv.y);
        if (lane == 0) unsafeAtomicAdd(s + (size_t)dst * NT + t, w);
    }
}

#define BM 64
#define BK 32
__global__ __launch_bounds__(256) void gemm_gelu_kernel(
    const float* __restrict__ x, const float* __restrict__ agg,
    const float* __restrict__ s, const float* __restrict__ wcat,
    const float* __restrict__ biasb, float* __restrict__ out, int nNodes) {
    __shared__ float As[BK][BM + 1];
    __shared__ float Bs[BK][D];

    int tx = threadIdx.x;
    int row0 = blockIdx.x * BM;
    int cg = tx & 31;
    int rg = tx >> 5;
    int lr = tx >> 3;
    int lc = (tx & 7) * 4;

    float acc[8][4];
#pragma unroll
    for (int i = 0; i < 8; ++i)
#pragma unroll
        for (int j = 0; j < 4; ++j) acc[i][j] = 0.f;

    for (int k0 = 0; k0 < KTOT; k0 += BK) {
        const float* srcBase;
        int strideA, koff;
        if (k0 < D) { srcBase = x; strideA = D; koff = k0; }
        else        { srcBase = agg; strideA = NT * D; koff = k0 - D; }
#pragma unroll
        for (int h = 0; h < 2; ++h) {
            int r = lr + h * 32;
            int node = row0 + r;
            if (node >= nNodes) node = nNodes - 1;
            float4 v = *(const float4*)(srcBase + (size_t)node * strideA + koff + lc);
            As[lc + 0][r] = v.x; As[lc + 1][r] = v.y;
            As[lc + 2][r] = v.z; As[lc + 3][r] = v.w;
        }
        {
            int br = tx >> 5;
            int bc = (tx & 31) * 4;
#pragma unroll
            for (int h = 0; h < 4; ++h) {
                int r = br + h * 8;
                *(float4*)(&Bs[r][bc]) = *(const float4*)(wcat + (size_t)(k0 + r) * D + bc);
            }
        }
        __syncthreads();
#pragma unroll
        for (int kk = 0; kk < BK; ++kk) {
            float4 b = *(const float4*)(&Bs[kk][cg * 4]);
            float a[8];
            *(float4*)(a)     = *(const float4*)(&As[kk][rg * 8]);
            *(float4*)(a + 4) = *(const float4*)(&As[kk][rg * 8 + 4]);
#pragma unroll
            for (int i = 0; i < 8; ++i) {
                acc[i][0] = fmaf(a[i], b.x, acc[i][0]);
                acc[i][1] = fmaf(a[i], b.y, acc[i][1]);
                acc[i][2] = fmaf(a[i], b.z, acc[i][2]);
                acc[i][3] = fmaf(a[i], b.w, acc[i][3]);
            }
        }
        __syncthreads();
    }

    int jc = cg * 4;
    float4 bb0 = *(const float4*)(biasb + 0 * D + jc);
    float4 bb1 = *(const float4*)(biasb + 1 * D + jc);
    float4 bb2 = *(const float4*)(biasb + 2 * D + jc);
    float4 bsv = *(const float4*)(biasb + NT * D + jc);
#pragma unroll
    for (int i = 0; i < 8; ++i) {
        int node = row0 + rg * 8 + i;
        if (node >= nNodes) break;
        float s0 = s[(size_t)node * NT + 0];
        float s1 = s[(size_t)node * NT + 1];
        float s2 = s[(size_t)node * NT + 2];
        float4 r;
        r.x = acc[i][0] + bsv.x + s0 * bb0.x + s1 * bb1.x + s2 * bb2.x;
        r.y = acc[i][1] + bsv.y + s0 * bb0.y + s1 * bb1.y + s2 * bb2.y;
        r.z = acc[i][2] + bsv.z + s0 * bb0.z + s1 * bb1.z + s2 * bb2.z;
        r.w = acc[i][3] + bsv.w + s0 * bb0.w + s1 * bb1.w + s2 * bb2.w;
        const float kInvSqrt2 = 0.70710678118654752440f;
        r.x = 0.5f * r.x * (1.f + erff(r.x * kInvSqrt2));
        r.y = 0.5f * r.y * (1.f + erff(r.y * kInvSqrt2));
        r.z = 0.5f * r.z * (1.f + erff(r.z * kInvSqrt2));
        r.w = 0.5f * r.w * (1.f + erff(r.w * kInvSqrt2));
        *(float4*)(out + (size_t)node * D + jc) = r;
    }
}

// ================= PATH C: zero-workspace fallback =================
__global__ __launch_bounds__(256) void selfmv_kernel(
    const float* __restrict__ x, const float* __restrict__ Ws,
    const float* __restrict__ bs, const float* __restrict__ attn,
    float* __restrict__ out, int nN) {
    float a0 = attn[0], a1 = attn[1], a2 = attn[2], a3 = attn[3];
    float m = fmaxf(fmaxf(a0, a1), fmaxf(a2, a3));
    float e3 = expf(a3 - m);
    float inv = 1.f / (expf(a0 - m) + expf(a1 - m) + expf(a2 - m) + e3);
    float at3 = e3 * inv;
    int wave = (blockIdx.x * blockDim.x + threadIdx.x) >> 6;
    int lane = threadIdx.x & 63;
    int nw = (gridDim.x * blockDim.x) >> 6;
    for (int n = wave; n < nN; n += nw) {
        float2 xr = *(const float2*)(x + (size_t)n * D + lane * 2);
        float acc0 = 0.f, acc1 = 0.f;
#pragma unroll
        for (int k = 0; k < D; ++k) {
            float xv = __shfl((k & 1) ? xr.y : xr.x, k >> 1);
            float2 wv = *(const float2*)(Ws + (size_t)k * D + lane * 2);
            acc0 = fmaf(xv, wv.x, acc0);
            acc1 = fmaf(xv, wv.y, acc1);
        }
        float2 r;
        r.x = at3 * (acc0 + bs[lane * 2]);
        r.y = at3 * (acc1 + bs[lane * 2 + 1]);
        *(float2*)(out + (size_t)n * D + lane * 2) = r;
    }
}

__global__ __launch_bounds__(256) void edgemv_kernel(
    const float* __restrict__ x, const int* __restrict__ ei,
    const int* __restrict__ et, const float* __restrict__ ew,
    const float* __restrict__ We, const float* __restrict__ be,
    const float* __restrict__ attn, float* __restrict__ out, int nE) {
    float a0 = attn[0], a1 = attn[1], a2 = attn[2], a3 = attn[3];
    float m = fmaxf(fmaxf(a0, a1), fmaxf(a2, a3));
    float e0 = expf(a0 - m), e1 = expf(a1 - m), e2 = expf(a2 - m), e3 = expf(a3 - m);
    float inv = 1.f / (e0 + e1 + e2 + e3);
    float at[NT] = {e0 * inv, e1 * inv, e2 * inv};
    int wave = (blockIdx.x * blockDim.x + threadIdx.x) >> 6;
    int lane = threadIdx.x & 63;
    int nw = (gridDim.x * blockDim.x) >> 6;
    for (int e = wave; e < nE; e += nw) {
        int src = ei[e];
        int dst = ei[nE + e];
        int t = et[e];
        float sc = ew[e] * at[t];
        const float* W = We + (size_t)t * D * D;
        float2 xr = *(const float2*)(x + (size_t)src * D + lane * 2);
        float acc0 = 0.f, acc1 = 0.f;
#pragma unroll
        for (int k = 0; k < D; ++k) {
            float xv = __shfl((k & 1) ? xr.y : xr.x, k >> 1);
            float2 wv = *(const float2*)(W + (size_t)k * D + lane * 2);
            acc0 = fmaf(xv, wv.x, acc0);
            acc1 = fmaf(xv, wv.y, acc1);
        }
        float* p = out + (size_t)dst * D + lane * 2;
        unsafeAtomicAdd(p,     sc * (acc0 + be[(size_t)t * D + lane * 2]));
        unsafeAtomicAdd(p + 1, sc * (acc1 + be[(size_t)t * D + lane * 2 + 1]));
    }
}

__global__ void gelu_kernel(float* __restrict__ p, long long n4) {
    long long i = (long long)blockIdx.x * blockDim.x + threadIdx.x;
    long long stride = (long long)gridDim.x * blockDim.x;
    const float kInvSqrt2 = 0.70710678118654752440f;
    for (; i < n4; i += stride) {
        float4 r = ((float4*)p)[i];
        r.x = 0.5f * r.x * (1.f + erff(r.x * kInvSqrt2));
        r.y = 0.5f * r.y * (1.f + erff(r.y * kInvSqrt2));
        r.z = 0.5f * r.z * (1.f + erff(r.z * kInvSqrt2));
        r.w = 0.5f * r.w * (1.f + erff(r.w * kInvSqrt2));
        ((float4*)p)[i] = r;
    }
}

extern "C" void kernel_launch(void* const* d_in, const int* in_sizes, int n_in,
                              void* d_out, int out_size, void* d_ws, size_t ws_size,
                              hipStream_t stream) {
    const float* x = (const float*)d_in[0];
    const int* ei = (const int*)d_in[1];      // int64 in reference -> int32 here
    const int* et = (const int*)d_in[2];
    const float* ew = (const float*)d_in[3];
    const float* W_edge = (const float*)d_in[4];
    const float* b_edge = (const float*)d_in[5];
    const float* W_self = (const float*)d_in[6];
    const float* b_self = (const float*)d_in[7];
    const float* attention = (const float*)d_in[8];
    float* out = (float*)d_out;

    const int nN = in_sizes[0] / D;   // 100000
    const int nE = in_sizes[2];       // 600000

    // ---- fused path workspace (16B-aligned sections) ----
    size_t off = 0;
    auto take = [&](size_t bytes) { size_t o = (off + 15) & ~(size_t)15; off = o + bytes; return o; };
    size_t o_wcat  = take((size_t)KTOT * D * 4);
    size_t o_biasb = take((size_t)KTOT * 4);
    size_t o_bfrag = take(131072);
    size_t o_deg   = take((size_t)(nN + 2) * 4);          // deg[nN] + ovfc
    size_t o_ovfl  = take((size_t)nE * 4);
    size_t o_csr   = take((size_t)nN * NCAP * 8);
    size_t o_xb    = take((size_t)nN * D * 2);
    size_t needFused = off;

    if (ws_size >= needFused && nN < (1 << 20)) {
        char* ws = (char*)d_ws;
        float* wcat = (float*)(ws + o_wcat);
        float* biasb = (float*)(ws + o_biasb);
        unsigned short* bfrag = (unsigned short*)(ws + o_bfrag);
        int* deg = (int*)(ws + o_deg);
        int* ovfc = deg + nN;
        int* ovfl = (int*)(ws + o_ovfl);
        int2* csr = (int2*)(ws + o_csr);
        unsigned short* xb = (unsigned short*)(ws + o_xb);

        hipLaunchKernelGGL(prep_kernel, dim3(64), dim3(256), 0, stream,
                           W_edge, b_edge, W_self, b_self, attention, wcat, biasb, bfrag,
                           deg, nN + 2);
        hipLaunchKernelGGL(xcvt_fill_kernel, dim3((nE + 255) / 256), dim3(256), 0, stream,
                           x, xb, nN, ei, et, ew, deg, csr, ovfc, ovfl, nE);
        hipLaunchKernelGGL(fused_gemm_kernel, dim3((nN + TM - 1) / TM), dim3(512), 0, stream,
                           xb, csr, deg, bfrag, biasb, ei, et, ew, ovfc, ovfl, out, nN, nE);
        return;
    }

    const size_t baseFloats = (size_t)nN * NT * D + (size_t)nN * NT + (size_t)KTOT * D + KTOT;
    if (ws_size >= baseFloats * 4) {
        float* agg = (float*)d_ws;
        float* sW = agg + (size_t)nN * NT * D;
        float* wcat = sW + (size_t)nN * NT;
        float* biasb = wcat + (size_t)KTOT * D;
        long long zeroFloats = (long long)nN * (NT * D + NT);
        hipLaunchKernelGGL(zero_kernel, dim3(2048), dim3(256), 0, stream, agg, (zeroFloats + 3) / 4);
        hipLaunchKernelGGL(prep_kernel, dim3(64), dim3(256), 0, stream,
                           W_edge, b_edge, W_self, b_self, attention, wcat, biasb,
                           (unsigned short*)nullptr, (int*)nullptr, 0);
        hipLaunchKernelGGL(scatterA_kernel, dim3(2048), dim3(256), 0, stream,
                           x, ei, et, ew, agg, sW, nE);
        hipLaunchKernelGGL(gemm_gelu_kernel, dim3((nN + BM - 1) / BM), dim3(256), 0, stream,
                           x, agg, sW, wcat, biasb, out, nN);
    } else {
        hipLaunchKernelGGL(selfmv_kernel, dim3(2048), dim3(256), 0, stream,
                           x, W_self, b_self, attention, out, nN);
        hipLaunchKernelGGL(edgemv_kernel, dim3(2048), dim3(256), 0, stream,
                           x, ei, et, ew, W_edge, b_edge, attention, out, nE);
        hipLaunchKernelGGL(gelu_kernel, dim3(2048), dim3(256), 0, stream,
                           out, (long long)nN * D / 4);
    }
}